// Round 1
// baseline (214.952 us; speedup 1.0000x reference)
//
#include <hip/hip_runtime.h>
#include <math.h>

#define EMB 32

// Fused BAHDANAU+ recommender scorer.
// Layout: 4 threads per element (t = tid&3 owns dims [8t, 8t+8)).
// Each 4-thread group processes 4 consecutive elements (q = 0..3) so the
// LDS weight reads (attn_W 384 + W1 768 floats) are amortized 4x.
// Block = 256 threads -> 64 groups -> 256 elements. Grid = B/256 = 512.
__global__ __launch_bounds__(256, 2) void bahdanau_fused(
    const int* __restrict__ group_inputs,   // [B]
    const int* __restrict__ item_inputs,    // [B]
    const int* __restrict__ members,        // [500000][3]
    const float* __restrict__ user_emb,     // [1000000][32]
    const float* __restrict__ item_emb,     // [100000][14]
    const float* __restrict__ genres,       // [100000][18]
    const float* __restrict__ attn_W,       // [128][3]
    const float* __restrict__ attn_b,       // [3]
    const float* __restrict__ pred_W1,      // [96][8]
    const float* __restrict__ pred_b1,      // [8]
    const float* __restrict__ pred_W2,      // [8][1]
    const float* __restrict__ pred_b2,      // [1]
    float* __restrict__ out)                // [B]
{
    __shared__ float s_aW[128 * 3];
    __shared__ float s_W1[96 * 8];
    __shared__ float s_ab[3];
    __shared__ float s_b1[8];
    __shared__ float s_W2[8];
    __shared__ float s_b2[1];

    const int tid = threadIdx.x;
    for (int i = tid; i < 384; i += 256) s_aW[i] = attn_W[i];
    for (int i = tid; i < 768; i += 256) s_W1[i] = pred_W1[i];
    if (tid < 3) s_ab[tid] = attn_b[tid];
    if (tid >= 4 && tid < 12) s_b1[tid - 4] = pred_b1[tid - 4];
    if (tid >= 12 && tid < 20) s_W2[tid - 12] = pred_W2[tid - 12];
    if (tid == 20) s_b2[0] = pred_b2[0];
    __syncthreads();

    const int t = tid & 3;          // sub-lane within 4-thread group
    const int grp = tid >> 2;       // group id within block (0..63)
    const int ebase = blockIdx.x * 256 + grp * 4;  // group's 4 elements
    const int dbase = t * 8;        // this thread's dim slice

    // Lane t loads the index data for element ebase+t, then broadcast.
    const int emine = ebase + t;
    const int gidx = group_inputs[emine];
    const int iidx = item_inputs[emine];
    const int mm0 = members[3 * gidx + 0];
    const int mm1 = members[3 * gidx + 1];
    const int mm2 = members[3 * gidx + 2];

    int itq[4], mq[4][3];
#pragma unroll
    for (int q = 0; q < 4; ++q) {
        itq[q]   = __shfl(iidx, q, 4);
        mq[q][0] = __shfl(mm0, q, 4);
        mq[q][1] = __shfl(mm1, q, 4);
        mq[q][2] = __shfl(mm2, q, 4);
    }

    // Member embedding gathers: mem[q][j][0..7], float4 x2 each (rows are
    // 128B-aligned, dbase*4 is 32B-aligned -> clean dwordx4 loads).
    float mem[4][3][8];
#pragma unroll
    for (int q = 0; q < 4; ++q)
#pragma unroll
        for (int j = 0; j < 3; ++j) {
            const float4* p =
                (const float4*)(user_emb + (size_t)mq[q][j] * EMB + dbase);
            float4 lo = p[0];
            float4 hi = p[1];
            mem[q][j][0] = lo.x; mem[q][j][1] = lo.y;
            mem[q][j][2] = lo.z; mem[q][j][3] = lo.w;
            mem[q][j][4] = hi.x; mem[q][j][5] = hi.y;
            mem[q][j][6] = hi.z; mem[q][j][7] = hi.w;
        }

    // Item vector dims dbase..dbase+7: d<14 from item_emb, else genres.
    // (Pointer-select then single load: no speculative OOB access.)
    float itv[4][8];
#pragma unroll
    for (int q = 0; q < 4; ++q)
#pragma unroll
        for (int i = 0; i < 8; ++i) {
            int d = dbase + i;
            const float* p = (d < 14)
                ? (item_emb + (size_t)itq[q] * 14 + d)
                : (genres + (size_t)itq[q] * 18 + (d - 14));
            itv[q][i] = *p;
        }

    // Attention logits aw[q][k] = gi . attn_W[:,k] (partial over our dims).
    // gi row index: j*32 + d for member j, 96 + d for item -> j=3 handles item.
    float aw[4][3];
#pragma unroll
    for (int q = 0; q < 4; ++q) { aw[q][0] = 0.f; aw[q][1] = 0.f; aw[q][2] = 0.f; }

#pragma unroll
    for (int i = 0; i < 8; ++i) {
        float w[4][3];
#pragma unroll
        for (int j = 0; j < 4; ++j) {
            int row = j * 32 + dbase + i;   // j==3 -> 96+d (item rows)
            w[j][0] = s_aW[row * 3 + 0];
            w[j][1] = s_aW[row * 3 + 1];
            w[j][2] = s_aW[row * 3 + 2];
        }
#pragma unroll
        for (int q = 0; q < 4; ++q)
#pragma unroll
            for (int k = 0; k < 3; ++k)
                aw[q][k] += mem[q][0][i] * w[0][k] + mem[q][1][i] * w[1][k]
                          + mem[q][2][i] * w[2][k] + itv[q][i] * w[3][k];
    }
    // Reduce partials across the 4 lanes (all lanes end with the full sum).
#pragma unroll
    for (int q = 0; q < 4; ++q)
#pragma unroll
        for (int k = 0; k < 3; ++k) {
            float v = aw[q][k];
            v += __shfl_xor(v, 1, 4);
            v += __shfl_xor(v, 2, 4);
            aw[q][k] = v + s_ab[k];
        }

    // g (our dim slice) per element: weighted member sum.
    float gv[4][8];
#pragma unroll
    for (int q = 0; q < 4; ++q)
#pragma unroll
        for (int i = 0; i < 8; ++i)
            gv[q][i] = aw[q][0] * mem[q][0][i] + aw[q][1] * mem[q][1][i]
                     + aw[q][2] * mem[q][2][i];

    // h partials: new = [g*it (rows 0-31), g (32-63), it (64-95)] @ W1[96][8].
    float ph[4][8];
#pragma unroll
    for (int q = 0; q < 4; ++q)
#pragma unroll
        for (int c = 0; c < 8; ++c) ph[q][c] = 0.f;

#pragma unroll
    for (int i = 0; i < 8; ++i) {
        int d = dbase + i;
        float w0[8], w1[8], w2[8];
#pragma unroll
        for (int c = 0; c < 8; ++c) {
            w0[c] = s_W1[d * 8 + c];
            w1[c] = s_W1[(32 + d) * 8 + c];
            w2[c] = s_W1[(64 + d) * 8 + c];
        }
#pragma unroll
        for (int q = 0; q < 4; ++q) {
            float a = gv[q][i] * itv[q][i];
            float b = gv[q][i];
            float cc = itv[q][i];
#pragma unroll
            for (int c = 0; c < 8; ++c)
                ph[q][c] += a * w0[c] + b * w1[c] + cc * w2[c];
        }
    }

    // Reduce h partials across the 4 lanes; lane t keeps element q==t.
    float hq[8];
#pragma unroll
    for (int q = 0; q < 4; ++q)
#pragma unroll
        for (int c = 0; c < 8; ++c) {
            float v = ph[q][c];
            v += __shfl_xor(v, 1, 4);
            v += __shfl_xor(v, 2, 4);
            if (q == t) hq[c] = v;
        }

    // Epilogue: relu -> W2 -> sigmoid. Lane t writes element ebase+t.
    float y = s_b2[0];
#pragma unroll
    for (int c = 0; c < 8; ++c) {
        float h = hq[c] + s_b1[c];
        h = fmaxf(h, 0.0f);
        y = fmaf(h, s_W2[c], y);
    }
    y = 1.0f / (1.0f + expf(-y));
    out[ebase + t] = y;
}

extern "C" void kernel_launch(void* const* d_in, const int* in_sizes, int n_in,
                              void* d_out, int out_size, void* d_ws, size_t ws_size,
                              hipStream_t stream) {
    const int*   group_inputs = (const int*)d_in[0];
    const int*   item_inputs  = (const int*)d_in[1];
    const int*   members      = (const int*)d_in[2];
    const float* user_emb     = (const float*)d_in[3];
    const float* item_emb     = (const float*)d_in[4];
    const float* genres       = (const float*)d_in[5];
    const float* attn_W       = (const float*)d_in[6];
    const float* attn_b       = (const float*)d_in[7];
    const float* pred_W1      = (const float*)d_in[8];
    const float* pred_b1      = (const float*)d_in[9];
    const float* pred_W2      = (const float*)d_in[10];
    const float* pred_b2      = (const float*)d_in[11];
    float* out = (float*)d_out;

    const int B = in_sizes[0];           // 131072; divisible by 256
    const int blocks = B / 256;          // 512 blocks, 256 elements each

    bahdanau_fused<<<blocks, 256, 0, stream>>>(
        group_inputs, item_inputs, members, user_emb, item_emb, genres,
        attn_W, attn_b, pred_W1, pred_b1, pred_W2, pred_b2, out);
}

// Round 2
// 214.892 us; speedup vs baseline: 1.0003x; 1.0003x over previous
//
#include <hip/hip_runtime.h>
#include <math.h>

#define EMB 32

// v2: lean-register, high-occupancy layout.
// 4 threads per element (t = tid&3 owns dims [8t, 8t+8)); each 4-thread
// group processes q=2 elements (LDS weight reads amortized 2x).
// Weights staged TRANSPOSED in LDS ([k][128] and [c][96]) so per-thread
// weight reads are contiguous ds_read_b128 with only 8 live weight regs.
// Block = 256 threads -> 64 groups -> 128 elements. Grid = B/128 = 1024.
// __launch_bounds__(256,4): target <=128 VGPRs -> 16 waves/CU for gather
// latency hiding (v1 at 8 waves/CU + ~230 VGPRs serialized cold gathers).
__global__ __launch_bounds__(256, 4) void bahdanau_fused(
    const int* __restrict__ group_inputs,   // [B]
    const int* __restrict__ item_inputs,    // [B]
    const int* __restrict__ members,        // [500000][3]
    const float* __restrict__ user_emb,     // [1000000][32]
    const float* __restrict__ item_emb,     // [100000][14]
    const float* __restrict__ genres,       // [100000][18]
    const float* __restrict__ attn_W,       // [128][3]
    const float* __restrict__ attn_b,       // [3]
    const float* __restrict__ pred_W1,      // [96][8]
    const float* __restrict__ pred_b1,      // [8]
    const float* __restrict__ pred_W2,      // [8][1]
    const float* __restrict__ pred_b2,      // [1]
    float* __restrict__ out)                // [B]
{
    __shared__ float s_aWT[3 * 128];   // [k][d]  transposed attn_W
    __shared__ float s_W1T[8 * 96];    // [c][r]  transposed pred_W1
    __shared__ float s_ab[3];
    __shared__ float s_b1[8];
    __shared__ float s_W2[8];
    __shared__ float s_b2[1];

    const int tid = threadIdx.x;
    for (int i = tid; i < 3 * 128; i += 256) {
        int k = i >> 7, d = i & 127;
        s_aWT[i] = attn_W[d * 3 + k];
    }
    for (int i = tid; i < 8 * 96; i += 256) {
        int c = i / 96, r = i - c * 96;
        s_W1T[i] = pred_W1[r * 8 + c];
    }
    if (tid < 3) s_ab[tid] = attn_b[tid];
    else if (tid < 11) s_b1[tid - 3] = pred_b1[tid - 3];
    else if (tid < 19) s_W2[tid - 11] = pred_W2[tid - 11];
    else if (tid == 19) s_b2[0] = pred_b2[0];
    __syncthreads();

    const int t = tid & 3;                          // dim-slice owner
    const int grp = tid >> 2;                       // 0..63
    const int ebase = blockIdx.x * 128 + grp * 2;   // group's 2 elements
    const int dbase = t * 8;

    // Index loads: same address across the group's 4 lanes (L1 broadcast);
    // no shuffle dependency chain.
    const int g0 = group_inputs[ebase], g1 = group_inputs[ebase + 1];
    const int i0 = item_inputs[ebase],  i1 = item_inputs[ebase + 1];
    int m0[3], m1[3];
#pragma unroll
    for (int j = 0; j < 3; ++j) {
        m0[j] = members[3 * g0 + j];
        m1[j] = members[3 * g1 + j];
    }

    // Member gathers: 12 independent dwordx4 loads (rows 128B-aligned).
    float mem0[3][8], mem1[3][8];
#pragma unroll
    for (int j = 0; j < 3; ++j) {
        const float4* p0 = (const float4*)(user_emb + (size_t)m0[j] * EMB + dbase);
        const float4* p1 = (const float4*)(user_emb + (size_t)m1[j] * EMB + dbase);
        float4 a = p0[0], b = p0[1], c = p1[0], d = p1[1];
        mem0[j][0] = a.x; mem0[j][1] = a.y; mem0[j][2] = a.z; mem0[j][3] = a.w;
        mem0[j][4] = b.x; mem0[j][5] = b.y; mem0[j][6] = b.z; mem0[j][7] = b.w;
        mem1[j][0] = c.x; mem1[j][1] = c.y; mem1[j][2] = c.z; mem1[j][3] = c.w;
        mem1[j][4] = d.x; mem1[j][5] = d.y; mem1[j][6] = d.z; mem1[j][7] = d.w;
    }

    // Item vector dims: d<14 from item_emb, else genres (address select, one load).
    float itv0[8], itv1[8];
#pragma unroll
    for (int i = 0; i < 8; ++i) {
        int d = dbase + i;
        const float* p0 = (d < 14) ? item_emb + (size_t)i0 * 14 + d
                                   : genres + (size_t)i0 * 18 + (d - 14);
        const float* p1 = (d < 14) ? item_emb + (size_t)i1 * 14 + d
                                   : genres + (size_t)i1 * 18 + (d - 14);
        itv0[i] = *p0;
        itv1[i] = *p1;
    }

    // Attention logits: aw[k] = sum_d gi[d]*attn_W[d][k]; gi rows:
    // member j at dims [32j,32j+32), item at [96,128).
    // Weight reads: contiguous 8-float chunks -> 2 ds_read_b128 each.
    float aw0[3], aw1[3];
#pragma unroll
    for (int k = 0; k < 3; ++k) {
        float a0 = 0.f, a1 = 0.f;
#pragma unroll
        for (int j = 0; j < 3; ++j) {
            const float4* wp = (const float4*)&s_aWT[k * 128 + j * 32 + dbase];
            float4 wl = wp[0], wh = wp[1];
            float w[8] = {wl.x, wl.y, wl.z, wl.w, wh.x, wh.y, wh.z, wh.w};
#pragma unroll
            for (int i = 0; i < 8; ++i) {
                a0 = fmaf(mem0[j][i], w[i], a0);
                a1 = fmaf(mem1[j][i], w[i], a1);
            }
        }
        {
            const float4* wp = (const float4*)&s_aWT[k * 128 + 96 + dbase];
            float4 wl = wp[0], wh = wp[1];
            float w[8] = {wl.x, wl.y, wl.z, wl.w, wh.x, wh.y, wh.z, wh.w};
#pragma unroll
            for (int i = 0; i < 8; ++i) {
                a0 = fmaf(itv0[i], w[i], a0);
                a1 = fmaf(itv1[i], w[i], a1);
            }
        }
        aw0[k] = a0; aw1[k] = a1;
    }
    // Reduce partial dots across the 4 lanes of the group; add bias.
#pragma unroll
    for (int k = 0; k < 3; ++k) {
        float v0 = aw0[k];
        v0 += __shfl_xor(v0, 1, 4);
        v0 += __shfl_xor(v0, 2, 4);
        aw0[k] = v0 + s_ab[k];
        float v1 = aw1[k];
        v1 += __shfl_xor(v1, 1, 4);
        v1 += __shfl_xor(v1, 2, 4);
        aw1[k] = v1 + s_ab[k];
    }

    // g (our dim slice): weighted member sum; also precompute g*it.
    float gv0[8], gv1[8], git0[8], git1[8];
#pragma unroll
    for (int i = 0; i < 8; ++i) {
        gv0[i] = aw0[0] * mem0[0][i] + aw0[1] * mem0[1][i] + aw0[2] * mem0[2][i];
        gv1[i] = aw1[0] * mem1[0][i] + aw1[1] * mem1[1][i] + aw1[2] * mem1[2][i];
        git0[i] = gv0[i] * itv0[i];
        git1[i] = gv1[i] * itv1[i];
    }

    // h partials: new = [g*it | g | it] (96) @ W1 -> 8; W1 transposed [c][96].
    float ph0[8], ph1[8];
#pragma unroll
    for (int c = 0; c < 8; ++c) {
        float a0 = 0.f, a1 = 0.f;
        const float4* wp0 = (const float4*)&s_W1T[c * 96 + dbase];
        const float4* wp1 = (const float4*)&s_W1T[c * 96 + 32 + dbase];
        const float4* wp2 = (const float4*)&s_W1T[c * 96 + 64 + dbase];
        float4 al = wp0[0], ah = wp0[1];
        float4 bl = wp1[0], bh = wp1[1];
        float4 cl = wp2[0], ch = wp2[1];
        float wa[8] = {al.x, al.y, al.z, al.w, ah.x, ah.y, ah.z, ah.w};
        float wb[8] = {bl.x, bl.y, bl.z, bl.w, bh.x, bh.y, bh.z, bh.w};
        float wc[8] = {cl.x, cl.y, cl.z, cl.w, ch.x, ch.y, ch.z, ch.w};
#pragma unroll
        for (int i = 0; i < 8; ++i) {
            a0 = fmaf(git0[i], wa[i], a0);
            a0 = fmaf(gv0[i],  wb[i], a0);
            a0 = fmaf(itv0[i], wc[i], a0);
            a1 = fmaf(git1[i], wa[i], a1);
            a1 = fmaf(gv1[i],  wb[i], a1);
            a1 = fmaf(itv1[i], wc[i], a1);
        }
        ph0[c] = a0; ph1[c] = a1;
    }

    // Reduce h partials; lane t (t<2) keeps element ebase+t.
    float hq[8];
#pragma unroll
    for (int c = 0; c < 8; ++c) {
        float v0 = ph0[c];
        v0 += __shfl_xor(v0, 1, 4);
        v0 += __shfl_xor(v0, 2, 4);
        float v1 = ph1[c];
        v1 += __shfl_xor(v1, 1, 4);
        v1 += __shfl_xor(v1, 2, 4);
        hq[c] = (t == 0) ? v0 : v1;
    }

    if (t < 2) {
        float y = s_b2[0];
#pragma unroll
        for (int c = 0; c < 8; ++c) {
            float h = fmaxf(hq[c] + s_b1[c], 0.0f);
            y = fmaf(h, s_W2[c], y);
        }
        y = 1.0f / (1.0f + expf(-y));
        out[ebase + t] = y;
    }
}

extern "C" void kernel_launch(void* const* d_in, const int* in_sizes, int n_in,
                              void* d_out, int out_size, void* d_ws, size_t ws_size,
                              hipStream_t stream) {
    const int*   group_inputs = (const int*)d_in[0];
    const int*   item_inputs  = (const int*)d_in[1];
    const int*   members      = (const int*)d_in[2];
    const float* user_emb     = (const float*)d_in[3];
    const float* item_emb     = (const float*)d_in[4];
    const float* genres       = (const float*)d_in[5];
    const float* attn_W       = (const float*)d_in[6];
    const float* attn_b       = (const float*)d_in[7];
    const float* pred_W1      = (const float*)d_in[8];
    const float* pred_b1      = (const float*)d_in[9];
    const float* pred_W2      = (const float*)d_in[10];
    const float* pred_b2      = (const float*)d_in[11];
    float* out = (float*)d_out;

    const int B = in_sizes[0];           // 131072
    const int blocks = B / 128;          // 1024 blocks, 128 elements each

    bahdanau_fused<<<blocks, 256, 0, stream>>>(
        group_inputs, item_inputs, members, user_emb, item_emb, genres,
        attn_W, attn_b, pred_W1, pred_b1, pred_W2, pred_b2, out);
}